// Round 1
// baseline (159.298 us; speedup 1.0000x reference)
//
#include <hip/hip_runtime.h>
#include <hip/hip_bf16.h>

typedef unsigned short u16;
typedef short s16x8 __attribute__((ext_vector_type(8)));
typedef float f32x4 __attribute__((ext_vector_type(4)));

// fp32 -> bf16 round-to-nearest-even
__device__ inline u16 f2bf(float f) {
  union { float f; unsigned int u; } v; v.f = f;
  unsigned int r = v.u + 0x7fffu + ((v.u >> 16) & 1u);
  return (u16)(r >> 16);
}

// ---------------------------------------------------------------- cast x -> bf16
__global__ __launch_bounds__(256) void cast_x_kernel(const float* __restrict__ x,
                                                     u16* __restrict__ xb) {
  int i = (blockIdx.x * 256 + threadIdx.x) * 8;
  float4 a = *(const float4*)(x + i);
  float4 b = *(const float4*)(x + i + 4);
  s16x8 o;
  o[0] = (short)f2bf(a.x); o[1] = (short)f2bf(a.y);
  o[2] = (short)f2bf(a.z); o[3] = (short)f2bf(a.w);
  o[4] = (short)f2bf(b.x); o[5] = (short)f2bf(b.y);
  o[6] = (short)f2bf(b.z); o[7] = (short)f2bf(b.w);
  *(s16x8*)(xb + i) = o;
}

// ---------------------------------------------------------------- W (512 x C) -> Wt bf16 (C x 512)
__global__ __launch_bounds__(256) void transpose_cast_w(const float* __restrict__ src, int C,
                                                        int rowoff, u16* __restrict__ wt) {
  __shared__ float tile[64][65];
  int j0 = blockIdx.x * 64, k0 = blockIdx.y * 64;
  int tx = threadIdx.x % 64, ty4 = threadIdx.x / 64;
#pragma unroll
  for (int p = 0; p < 16; ++p) {
    int r = p * 4 + ty4;
    tile[r][tx] = src[(size_t)(k0 + r) * C + j0 + tx];
  }
  __syncthreads();
#pragma unroll
  for (int p = 0; p < 16; ++p) {
    int r = p * 4 + ty4;
    wt[(size_t)(rowoff + j0 + r) * 512 + k0 + tx] = f2bf(tile[tx][r]);
  }
}

// ---------------------------------------------------------------- fused QKV projection GEMM
// C[m][j] = sum_k xb[m][k] * W[k][j] + bias[j], m in [0,4096), j in [0,2560)
// j in [0,1024): q -> qa[b][h][n][128]; [1024,2048): k -> ka; [2048,2560): v -> va^T [b][h][d][n]
__global__ __launch_bounds__(256, 2) void gemm_qkv(const u16* __restrict__ xb, const u16* __restrict__ wt,
                                                   const float* __restrict__ bq, const float* __restrict__ bk,
                                                   const float* __restrict__ bv,
                                                   u16* __restrict__ qa, u16* __restrict__ ka,
                                                   u16* __restrict__ va) {
  __shared__ __align__(16) u16 As[128 * 72];
  __shared__ __align__(16) u16 Bs[128 * 72];
  int m0 = blockIdx.x * 128, j0 = blockIdx.y * 128;
  int tid = threadIdx.x;
  int w = tid >> 6, lane = tid & 63, quad = lane >> 4, l16 = lane & 15;
  int wr = (w >> 1) * 64, wc = (w & 1) * 64;

  f32x4 acc[4][4];
#pragma unroll
  for (int i = 0; i < 4; ++i)
#pragma unroll
    for (int j = 0; j < 4; ++j)
#pragma unroll
      for (int r = 0; r < 4; ++r) acc[i][j][r] = 0.f;

  for (int kk = 0; kk < 8; ++kk) {
    int k0 = kk * 64;
    __syncthreads();
#pragma unroll
    for (int i = 0; i < 4; ++i) {
      int c = tid * 4 + i;            // 1024 chunks of 8 shorts
      int row = c >> 3, cc = c & 7;
      *(int4*)(&As[row * 72 + cc * 8]) = *(const int4*)(xb + (size_t)(m0 + row) * 512 + k0 + cc * 8);
      *(int4*)(&Bs[row * 72 + cc * 8]) = *(const int4*)(wt + (size_t)(j0 + row) * 512 + k0 + cc * 8);
    }
    __syncthreads();
#pragma unroll
    for (int kb = 0; kb < 2; ++kb) {
      s16x8 af[4], bf[4];
#pragma unroll
      for (int rb = 0; rb < 4; ++rb)
        af[rb] = *(const s16x8*)(&As[(wr + rb * 16 + l16) * 72 + kb * 32 + quad * 8]);
#pragma unroll
      for (int cb = 0; cb < 4; ++cb)
        bf[cb] = *(const s16x8*)(&Bs[(wc + cb * 16 + l16) * 72 + kb * 32 + quad * 8]);
#pragma unroll
      for (int rb = 0; rb < 4; ++rb)
#pragma unroll
        for (int cb = 0; cb < 4; ++cb)
          acc[rb][cb] = __builtin_amdgcn_mfma_f32_16x16x32_bf16(af[rb], bf[cb], acc[rb][cb], 0, 0, 0);
    }
  }

#pragma unroll
  for (int cb = 0; cb < 4; ++cb) {
    int j = j0 + wc + cb * 16 + l16;
    float bias = (j < 1024) ? bq[j] : (j < 2048) ? bk[j - 1024] : bv[j - 2048];
#pragma unroll
    for (int rb = 0; rb < 4; ++rb) {
#pragma unroll
      for (int r = 0; r < 4; ++r) {
        int m = m0 + wr + rb * 16 + quad * 4 + r;
        int bidx = m >> 10, n = m & 1023;
        u16 o = f2bf(acc[rb][cb][r] + bias);
        if (j < 1024) {                       // q: h = j/128, col = j%128
          int h = j >> 7, r2 = j & 127;
          qa[((size_t)((bidx * 8 + h) * 1024 + n)) * 128 + r2] = o;
        } else if (j < 2048) {
          int jj = j - 1024, h = jj >> 7, r2 = jj & 127;
          ka[((size_t)((bidx * 8 + h) * 1024 + n)) * 128 + r2] = o;
        } else {                              // v transposed: [b][h][d][n]
          int jj = j - 2048, h = jj >> 6, d = jj & 63;
          va[((size_t)((bidx * 8 + h) * 64 + d)) * 1024 + n] = o;
        }
      }
    }
  }
}

// ---------------------------------------------------------------- differential attention
// grid (B*H, N/64); block 256 = 4 waves, wave w owns Q rows q0+16w .. +15.
// No-max softmax (scores bounded): O = sum exp(s) V, l via ones-column, out = O1/l1 - 0.5*O2/l2.
__global__ __launch_bounds__(256, 2) void attn_kernel(const u16* __restrict__ qa, const u16* __restrict__ ka,
                                                      const u16* __restrict__ va, float* __restrict__ out) {
  __shared__ __align__(16) u16 Ks[64 * 136];  // K-tile rows n, cols 0..127 (k1|k2), pad 8
  __shared__ __align__(16) u16 Vs[64 * 72];   // V^T tile [d][n], pad 8
  __shared__ __align__(16) u16 Ps[64 * 72];   // P round-trip, wave-private 16-row slabs
  int bh = blockIdx.x, b = bh >> 3, h = bh & 7;
  int q0 = blockIdx.y * 64;
  int tid = threadIdx.x, w = tid >> 6, lane = tid & 63, quad = lane >> 4, l16 = lane & 15;

  const u16* qrow = qa + (size_t)(bh * 1024 + q0 + w * 16 + l16) * 128;
  s16x8 q1f[2], q2f[2];
  q1f[0] = *(const s16x8*)(qrow + quad * 8);
  q1f[1] = *(const s16x8*)(qrow + 32 + quad * 8);
  q2f[0] = *(const s16x8*)(qrow + 64 + quad * 8);
  q2f[1] = *(const s16x8*)(qrow + 96 + quad * 8);

  f32x4 O1[5], O2[5];
#pragma unroll
  for (int i = 0; i < 5; ++i)
#pragma unroll
    for (int r = 0; r < 4; ++r) { O1[i][r] = 0.f; O2[i][r] = 0.f; }

  s16x8 onesf;   // B-frag of the ones column (col 64): 1.0 only for lanes with l16==0
#pragma unroll
  for (int i = 0; i < 8; ++i) onesf[i] = (l16 == 0) ? (short)0x3F80 : (short)0;

  for (int kt = 0; kt < 16; ++kt) {
    int n0 = kt * 64;
    __syncthreads();
#pragma unroll
    for (int i = 0; i < 4; ++i) {             // stage K tile: 64 rows x 16 chunks
      int c = tid * 4 + i, row = c >> 4, cc = c & 15;
      *(int4*)(&Ks[row * 136 + cc * 8]) = *(const int4*)(ka + (size_t)(bh * 1024 + n0 + row) * 128 + cc * 8);
    }
#pragma unroll
    for (int i = 0; i < 2; ++i) {             // stage V^T tile: 64 rows x 8 chunks
      int c = tid * 2 + i, row = c >> 3, cc = c & 7;
      *(int4*)(&Vs[row * 72 + cc * 8]) = *(const int4*)(va + (size_t)(bh * 64 + row) * 1024 + n0 + cc * 8);
    }
    __syncthreads();

    s16x8 vf[4][2];
#pragma unroll
    for (int ct = 0; ct < 4; ++ct)
#pragma unroll
      for (int kb = 0; kb < 2; ++kb)
        vf[ct][kb] = *(const s16x8*)(&Vs[(ct * 16 + l16) * 72 + kb * 32 + quad * 8]);

    // ---- half 1: q1.k1 ----
    {
#pragma unroll
      for (int nt = 0; nt < 4; ++nt) {
        f32x4 sv; sv[0] = sv[1] = sv[2] = sv[3] = 0.f;
#pragma unroll
        for (int kb = 0; kb < 2; ++kb) {
          s16x8 kf = *(const s16x8*)(&Ks[(nt * 16 + l16) * 136 + kb * 32 + quad * 8]);
          sv = __builtin_amdgcn_mfma_f32_16x16x32_bf16(q1f[kb], kf, sv, 0, 0, 0);
        }
#pragma unroll
        for (int r = 0; r < 4; ++r)
          Ps[(w * 16 + quad * 4 + r) * 72 + nt * 16 + l16] = f2bf(__expf(sv[r] * 0.125f));
      }
      asm volatile("s_waitcnt lgkmcnt(0)" ::: "memory");  // P writes retired before re-read
      s16x8 pf0 = *(const s16x8*)(&Ps[(w * 16 + l16) * 72 + quad * 8]);
      s16x8 pf1 = *(const s16x8*)(&Ps[(w * 16 + l16) * 72 + 32 + quad * 8]);
#pragma unroll
      for (int ct = 0; ct < 5; ++ct) {
        s16x8 b0 = (ct < 4) ? vf[ct][0] : onesf;
        s16x8 b1 = (ct < 4) ? vf[ct][1] : onesf;
        O1[ct] = __builtin_amdgcn_mfma_f32_16x16x32_bf16(pf0, b0, O1[ct], 0, 0, 0);
        O1[ct] = __builtin_amdgcn_mfma_f32_16x16x32_bf16(pf1, b1, O1[ct], 0, 0, 0);
      }
      asm volatile("" ::: "memory");
    }
    // ---- half 2: q2.k2 ----
    {
#pragma unroll
      for (int nt = 0; nt < 4; ++nt) {
        f32x4 sv; sv[0] = sv[1] = sv[2] = sv[3] = 0.f;
#pragma unroll
        for (int kb = 0; kb < 2; ++kb) {
          s16x8 kf = *(const s16x8*)(&Ks[(nt * 16 + l16) * 136 + 64 + kb * 32 + quad * 8]);
          sv = __builtin_amdgcn_mfma_f32_16x16x32_bf16(q2f[kb], kf, sv, 0, 0, 0);
        }
#pragma unroll
        for (int r = 0; r < 4; ++r)
          Ps[(w * 16 + quad * 4 + r) * 72 + nt * 16 + l16] = f2bf(__expf(sv[r] * 0.125f));
      }
      asm volatile("s_waitcnt lgkmcnt(0)" ::: "memory");
      s16x8 pf0 = *(const s16x8*)(&Ps[(w * 16 + l16) * 72 + quad * 8]);
      s16x8 pf1 = *(const s16x8*)(&Ps[(w * 16 + l16) * 72 + 32 + quad * 8]);
#pragma unroll
      for (int ct = 0; ct < 5; ++ct) {
        s16x8 b0 = (ct < 4) ? vf[ct][0] : onesf;
        s16x8 b1 = (ct < 4) ? vf[ct][1] : onesf;
        O2[ct] = __builtin_amdgcn_mfma_f32_16x16x32_bf16(pf0, b0, O2[ct], 0, 0, 0);
        O2[ct] = __builtin_amdgcn_mfma_f32_16x16x32_bf16(pf1, b1, O2[ct], 0, 0, 0);
      }
      asm volatile("" ::: "memory");
    }
  }

  // epilogue: broadcast denominators (col 64 lives in lanes with l16==0), normalize, combine
  float inv1[4], inv2[4];
#pragma unroll
  for (int r = 0; r < 4; ++r) {
    float l1 = __shfl(O1[4][r], lane & 48, 64);
    float l2 = __shfl(O2[4][r], lane & 48, 64);
    inv1[r] = 1.0f / l1;
    inv2[r] = 1.0f / l2;
  }
  int nb = q0 + w * 16 + quad * 4;
#pragma unroll
  for (int ct = 0; ct < 4; ++ct)
#pragma unroll
    for (int r = 0; r < 4; ++r) {
      float val = O1[ct][r] * inv1[r] - 0.5f * O2[ct][r] * inv2[r];
      out[(size_t)(b * 1024 + nb + r) * 512 + h * 64 + ct * 16 + l16] = val;
    }
}

// ---------------------------------------------------------------- launcher
extern "C" void kernel_launch(void* const* d_in, const int* in_sizes, int n_in,
                              void* d_out, int out_size, void* d_ws, size_t ws_size,
                              hipStream_t stream) {
  (void)in_sizes; (void)n_in; (void)out_size; (void)ws_size;
  const float* x  = (const float*)d_in[0];
  const float* Wq = (const float*)d_in[1];
  const float* bq = (const float*)d_in[2];
  const float* Wk = (const float*)d_in[3];
  const float* bk = (const float*)d_in[4];
  const float* Wv = (const float*)d_in[5];
  const float* bv = (const float*)d_in[6];
  float* out = (float*)d_out;

  char* ws = (char*)d_ws;
  u16* xb = (u16*)(ws);                    // 4096*512*2   = 4 MiB
  u16* wt = (u16*)(ws + 4194304);          // 2560*512*2   = 2.5 MiB
  u16* qa = (u16*)(ws + 6815744);          // 4*8*1024*128*2 = 8 MiB
  u16* ka = (u16*)(ws + 15204352);         // 8 MiB
  u16* va = (u16*)(ws + 23592960);         // 4*8*64*1024*2 = 4 MiB

  cast_x_kernel<<<1024, 256, 0, stream>>>(x, xb);
  transpose_cast_w<<<dim3(16, 8), 256, 0, stream>>>(Wq, 1024, 0, wt);
  transpose_cast_w<<<dim3(16, 8), 256, 0, stream>>>(Wk, 1024, 1024, wt);
  transpose_cast_w<<<dim3(8, 8), 256, 0, stream>>>(Wv, 512, 2048, wt);
  gemm_qkv<<<dim3(32, 20), 256, 0, stream>>>(xb, wt, bq, bk, bv, qa, ka, va);
  attn_kernel<<<dim3(32, 16), 256, 0, stream>>>(qa, ka, va, out);
}

// Round 2
// 139.208 us; speedup vs baseline: 1.1443x; 1.1443x over previous
//
#include <hip/hip_runtime.h>
#include <hip/hip_bf16.h>

typedef unsigned short u16;
typedef short s16x8 __attribute__((ext_vector_type(8)));
typedef float f32x4 __attribute__((ext_vector_type(4)));

// fp32 -> bf16 round-to-nearest-even
__device__ inline u16 f2bf(float f) {
  union { float f; unsigned int u; } v; v.f = f;
  unsigned int r = v.u + 0x7fffu + ((v.u >> 16) & 1u);
  return (u16)(r >> 16);
}

// async 16B global -> LDS DMA (lane i of the wave lands at ldsbase + i*16)
__device__ __forceinline__ void g2lds16(const u16* g, u16* l) {
  __builtin_amdgcn_global_load_lds((const __attribute__((address_space(1))) void*)g,
                                   (__attribute__((address_space(3))) void*)l, 16, 0, 0);
}

// ---------------------------------------------------------------- cast x -> bf16
__global__ __launch_bounds__(256) void cast_x_kernel(const float* __restrict__ x,
                                                     u16* __restrict__ xb) {
  int i = (blockIdx.x * 256 + threadIdx.x) * 8;
  float4 a = *(const float4*)(x + i);
  float4 b = *(const float4*)(x + i + 4);
  s16x8 o;
  o[0] = (short)f2bf(a.x); o[1] = (short)f2bf(a.y);
  o[2] = (short)f2bf(a.z); o[3] = (short)f2bf(a.w);
  o[4] = (short)f2bf(b.x); o[5] = (short)f2bf(b.y);
  o[6] = (short)f2bf(b.z); o[7] = (short)f2bf(b.w);
  *(s16x8*)(xb + i) = o;
}

// ---------------------------------------------------------------- W (512 x C) -> Wt bf16 (C x 512)
__global__ __launch_bounds__(256) void transpose_cast_w(const float* __restrict__ src, int C,
                                                        int rowoff, u16* __restrict__ wt) {
  __shared__ float tile[64][65];
  int j0 = blockIdx.x * 64, k0 = blockIdx.y * 64;
  int tx = threadIdx.x % 64, ty4 = threadIdx.x / 64;
#pragma unroll
  for (int p = 0; p < 16; ++p) {
    int r = p * 4 + ty4;
    tile[r][tx] = src[(size_t)(k0 + r) * C + j0 + tx];
  }
  __syncthreads();
#pragma unroll
  for (int p = 0; p < 16; ++p) {
    int r = p * 4 + ty4;
    wt[(size_t)(rowoff + j0 + r) * 512 + k0 + tx] = f2bf(tile[tx][r]);
  }
}

// ---------------------------------------------------------------- fused QKV projection GEMM (m97 recipe)
// LDS tiles 128 rows x 64 k, unpadded; 16B chunks XOR-swizzled by (row&7) so both the
// DMA landing pattern and b128 fragment reads are conflict-free.
__global__ __launch_bounds__(256, 2) void gemm_qkv(const u16* __restrict__ xb, const u16* __restrict__ wt,
                                                   const float* __restrict__ bq, const float* __restrict__ bk,
                                                   const float* __restrict__ bv,
                                                   u16* __restrict__ qa, u16* __restrict__ ka,
                                                   u16* __restrict__ va) {
  __shared__ __align__(16) u16 As[128 * 64];
  __shared__ __align__(16) u16 Bs[128 * 64];
  int m0 = blockIdx.x * 128, j0 = blockIdx.y * 128;
  int tid = threadIdx.x;
  int w = tid >> 6, lane = tid & 63, quad = lane >> 4, l16 = lane & 15;
  int wr = (w >> 1) * 64, wc = (w & 1) * 64;

  // staging: slot s = it*256+tid; physical chunk = s&7, row = s>>3, logical chunk = (s&7)^(row&7)
  int srow[4], scol[4], sbase[4];
#pragma unroll
  for (int it = 0; it < 4; ++it) {
    int s = it * 256 + tid;
    srow[it] = s >> 3;
    scol[it] = (s & 7) ^ ((s >> 3) & 7);
    sbase[it] = (s & ~63) * 8;       // wave-uniform LDS base (u16 units)
  }

  f32x4 acc[4][4];
#pragma unroll
  for (int i = 0; i < 4; ++i)
#pragma unroll
    for (int j = 0; j < 4; ++j)
#pragma unroll
      for (int r = 0; r < 4; ++r) acc[i][j][r] = 0.f;

  for (int kk = 0; kk < 8; ++kk) {
    int k0 = kk * 64;
    __syncthreads();                 // prev iteration's LDS reads done
#pragma unroll
    for (int it = 0; it < 4; ++it) {
      g2lds16(xb + (size_t)(m0 + srow[it]) * 512 + k0 + scol[it] * 8, &As[sbase[it]]);
      g2lds16(wt + (size_t)(j0 + srow[it]) * 512 + k0 + scol[it] * 8, &Bs[sbase[it]]);
    }
    __syncthreads();                 // barrier drain completes the DMA
#pragma unroll
    for (int kb = 0; kb < 2; ++kb) {
      s16x8 af[4], bfr[4];
#pragma unroll
      for (int rb = 0; rb < 4; ++rb) {
        int row = wr + rb * 16 + l16;
        af[rb] = *(const s16x8*)(&As[row * 64 + (((kb * 4 + quad) ^ (row & 7)) * 8)]);
      }
#pragma unroll
      for (int cb = 0; cb < 4; ++cb) {
        int row = wc + cb * 16 + l16;
        bfr[cb] = *(const s16x8*)(&Bs[row * 64 + (((kb * 4 + quad) ^ (row & 7)) * 8)]);
      }
#pragma unroll
      for (int rb = 0; rb < 4; ++rb)
#pragma unroll
        for (int cb = 0; cb < 4; ++cb)
          acc[rb][cb] = __builtin_amdgcn_mfma_f32_16x16x32_bf16(af[rb], bfr[cb], acc[rb][cb], 0, 0, 0);
    }
  }

#pragma unroll
  for (int cb = 0; cb < 4; ++cb) {
    int j = j0 + wc + cb * 16 + l16;
    float bias = (j < 1024) ? bq[j] : (j < 2048) ? bk[j - 1024] : bv[j - 2048];
#pragma unroll
    for (int rb = 0; rb < 4; ++rb) {
#pragma unroll
      for (int r = 0; r < 4; ++r) {
        int m = m0 + wr + rb * 16 + quad * 4 + r;
        int bidx = m >> 10, n = m & 1023;
        u16 o = f2bf(acc[rb][cb][r] + bias);
        if (j < 1024) {                       // q: h = j/128, col = j%128
          int h = j >> 7, r2 = j & 127;
          qa[((size_t)((bidx * 8 + h) * 1024 + n)) * 128 + r2] = o;
        } else if (j < 2048) {
          int jj = j - 1024, h = jj >> 7, r2 = jj & 127;
          ka[((size_t)((bidx * 8 + h) * 1024 + n)) * 128 + r2] = o;
        } else {                              // v transposed: [b][h][d][n]
          int jj = j - 2048, h = jj >> 6, d = jj & 63;
          va[((size_t)((bidx * 8 + h) * 64 + d)) * 1024 + n] = o;
        }
      }
    }
  }
}

// ---------------------------------------------------------------- differential attention v2
// Double-buffered K/V staging via global_load_lds (prefetch issued before compute),
// one barrier per K-tile, both halves merged around a single P LDS round-trip.
__global__ __launch_bounds__(256, 2) void attn_kernel(const u16* __restrict__ qa, const u16* __restrict__ ka,
                                                      const u16* __restrict__ va, float* __restrict__ out) {
  __shared__ __align__(16) u16 Ks[2][64 * 128];  // [n][128 cols k1|k2], XOR-swizzled chunks
  __shared__ __align__(16) u16 Vs[2][64 * 64];   // V^T [d][n], XOR-swizzled chunks
  __shared__ __align__(16) u16 Ps[2][64 * 72];   // per half, wave-private 16-row slabs, pad 8
  int bh = blockIdx.x, b = bh >> 3, h = bh & 7;
  int q0 = blockIdx.y * 64;
  int tid = threadIdx.x, w = tid >> 6, lane = tid & 63, quad = lane >> 4, l16 = lane & 15;

  const u16* qrow = qa + (size_t)(bh * 1024 + q0 + w * 16 + l16) * 128;
  s16x8 qf[2][2];
  qf[0][0] = *(const s16x8*)(qrow + quad * 8);
  qf[0][1] = *(const s16x8*)(qrow + 32 + quad * 8);
  qf[1][0] = *(const s16x8*)(qrow + 64 + quad * 8);
  qf[1][1] = *(const s16x8*)(qrow + 96 + quad * 8);

  f32x4 O1[5], O2[5];
#pragma unroll
  for (int i = 0; i < 5; ++i)
#pragma unroll
    for (int r = 0; r < 4; ++r) { O1[i][r] = 0.f; O2[i][r] = 0.f; }

  s16x8 onesf;   // B-frag of ones column: 1.0 only for lanes with l16==0
#pragma unroll
  for (int i = 0; i < 8; ++i) onesf[i] = (l16 == 0) ? (short)0x3F80 : (short)0;

  // staging slot precompute: Ks 1024 slots (4/thread), Vs 512 slots (2/thread)
  int krow[4], kcol[4], kbse[4];
#pragma unroll
  for (int it = 0; it < 4; ++it) {
    int s = it * 256 + tid;
    krow[it] = s >> 4; kcol[it] = (s & 15) ^ ((s >> 4) & 7); kbse[it] = (s & ~63) * 8;
  }
  int vrow[2], vcol[2], vbse[2];
#pragma unroll
  for (int it = 0; it < 2; ++it) {
    int s = it * 256 + tid;
    vrow[it] = s >> 3; vcol[it] = (s & 7) ^ ((s >> 3) & 7); vbse[it] = (s & ~63) * 8;
  }
  const u16* kgbase = ka + (size_t)bh * 1024 * 128;
  const u16* vgbase = va + (size_t)bh * 64 * 1024;

  auto stage = [&](int kt, int bufi) {
    int n0 = kt * 64;
#pragma unroll
    for (int it = 0; it < 4; ++it)
      g2lds16(kgbase + (size_t)(n0 + krow[it]) * 128 + kcol[it] * 8, &Ks[bufi][kbse[it]]);
#pragma unroll
    for (int it = 0; it < 2; ++it)
      g2lds16(vgbase + (size_t)vrow[it] * 1024 + n0 + vcol[it] * 8, &Vs[bufi][vbse[it]]);
  };

  stage(0, 0);
  __syncthreads();   // drain DMA for tile 0

  for (int kt = 0; kt < 16; ++kt) {
    int cur = kt & 1;
    if (kt < 15) stage(kt + 1, cur ^ 1);   // prefetch next tile; completes at loop-end barrier

    s16x8 vf[4][2];
#pragma unroll
    for (int ct = 0; ct < 4; ++ct)
#pragma unroll
      for (int kb = 0; kb < 2; ++kb) {
        int row = ct * 16 + l16;
        vf[ct][kb] = *(const s16x8*)(&Vs[cur][row * 64 + (((kb * 4 + quad) ^ (row & 7)) * 8)]);
      }

    // QK^T for both halves -> exp -> Ps (wave-private rows, no barrier needed)
#pragma unroll
    for (int hh = 0; hh < 2; ++hh) {
#pragma unroll
      for (int nt = 0; nt < 4; ++nt) {
        f32x4 sv; sv[0] = sv[1] = sv[2] = sv[3] = 0.f;
#pragma unroll
        for (int kb = 0; kb < 2; ++kb) {
          int row = nt * 16 + l16;
          s16x8 kf = *(const s16x8*)(&Ks[cur][row * 128 + (((hh * 8 + kb * 4 + quad) ^ (row & 7)) * 8)]);
          sv = __builtin_amdgcn_mfma_f32_16x16x32_bf16(qf[hh][kb], kf, sv, 0, 0, 0);
        }
#pragma unroll
        for (int r = 0; r < 4; ++r)
          Ps[hh][(w * 16 + quad * 4 + r) * 72 + nt * 16 + l16] = f2bf(__expf(sv[r] * 0.125f));
      }
    }
    asm volatile("s_waitcnt lgkmcnt(0)" ::: "memory");  // single round-trip drain for both halves
    s16x8 pf[2][2];
#pragma unroll
    for (int hh = 0; hh < 2; ++hh) {
      pf[hh][0] = *(const s16x8*)(&Ps[hh][(w * 16 + l16) * 72 + quad * 8]);
      pf[hh][1] = *(const s16x8*)(&Ps[hh][(w * 16 + l16) * 72 + 32 + quad * 8]);
    }
#pragma unroll
    for (int ct = 0; ct < 5; ++ct) {
      s16x8 b0 = (ct < 4) ? vf[ct][0] : onesf;
      s16x8 b1 = (ct < 4) ? vf[ct][1] : onesf;
      O1[ct] = __builtin_amdgcn_mfma_f32_16x16x32_bf16(pf[0][0], b0, O1[ct], 0, 0, 0);
      O1[ct] = __builtin_amdgcn_mfma_f32_16x16x32_bf16(pf[0][1], b1, O1[ct], 0, 0, 0);
      O2[ct] = __builtin_amdgcn_mfma_f32_16x16x32_bf16(pf[1][0], b0, O2[ct], 0, 0, 0);
      O2[ct] = __builtin_amdgcn_mfma_f32_16x16x32_bf16(pf[1][1], b1, O2[ct], 0, 0, 0);
    }
    __syncthreads();   // drains prefetch DMA + protects LDS buffer reuse
  }

  // epilogue: broadcast denominators (ones-column sits in lanes with l16==0), normalize, combine
  float inv1[4], inv2[4];
#pragma unroll
  for (int r = 0; r < 4; ++r) {
    float l1 = __shfl(O1[4][r], lane & 48, 64);
    float l2 = __shfl(O2[4][r], lane & 48, 64);
    inv1[r] = 1.0f / l1;
    inv2[r] = 1.0f / l2;
  }
  int nb = q0 + w * 16 + quad * 4;
#pragma unroll
  for (int ct = 0; ct < 4; ++ct)
#pragma unroll
    for (int r = 0; r < 4; ++r) {
      float val = O1[ct][r] * inv1[r] - 0.5f * O2[ct][r] * inv2[r];
      out[(size_t)(b * 1024 + nb + r) * 512 + h * 64 + ct * 16 + l16] = val;
    }
}

// ---------------------------------------------------------------- launcher
extern "C" void kernel_launch(void* const* d_in, const int* in_sizes, int n_in,
                              void* d_out, int out_size, void* d_ws, size_t ws_size,
                              hipStream_t stream) {
  (void)in_sizes; (void)n_in; (void)out_size; (void)ws_size;
  const float* x  = (const float*)d_in[0];
  const float* Wq = (const float*)d_in[1];
  const float* bq = (const float*)d_in[2];
  const float* Wk = (const float*)d_in[3];
  const float* bk = (const float*)d_in[4];
  const float* Wv = (const float*)d_in[5];
  const float* bv = (const float*)d_in[6];
  float* out = (float*)d_out;

  char* ws = (char*)d_ws;
  u16* xb = (u16*)(ws);                    // 4096*512*2   = 4 MiB
  u16* wt = (u16*)(ws + 4194304);          // 2560*512*2   = 2.5 MiB
  u16* qa = (u16*)(ws + 6815744);          // 4*8*1024*128*2 = 8 MiB
  u16* ka = (u16*)(ws + 15204352);         // 8 MiB
  u16* va = (u16*)(ws + 23592960);         // 4*8*64*1024*2 = 4 MiB

  cast_x_kernel<<<1024, 256, 0, stream>>>(x, xb);
  transpose_cast_w<<<dim3(16, 8), 256, 0, stream>>>(Wq, 1024, 0, wt);
  transpose_cast_w<<<dim3(16, 8), 256, 0, stream>>>(Wk, 1024, 1024, wt);
  transpose_cast_w<<<dim3(8, 8), 256, 0, stream>>>(Wv, 512, 2048, wt);
  gemm_qkv<<<dim3(32, 20), 256, 0, stream>>>(xb, wt, bq, bk, bv, qa, ka, va);
  attn_kernel<<<dim3(32, 16), 256, 0, stream>>>(qa, ka, va, out);
}